// Round 1
// baseline (404.245 us; speedup 1.0000x reference)
//
#include <hip/hip_runtime.h>

#define H 4
#define DIN 128
#define DOUT 64
#define EIN 16
#define EOUT 16
#define NEG_SLOPE 0.2f

// ---------------- W_l transpose: Wt[k][j] = W_l[j][k], [128][256] ----------
__global__ __launch_bounds__(256) void k_transW(const float* __restrict__ Wl,
                                                float* __restrict__ Wt) {
  int i = blockIdx.x * 256 + threadIdx.x;
  if (i < 256 * 128) {
    int j = i >> 7, k = i & 127;
    Wt[k * 256 + j] = Wl[i];
  }
}

// ---------------- node projection: xl[N][256] = x[N][128] @ Wt[128][256] ---
// tile 64 (M) x 64 (N), K=128 in 2 chunks of 64. 256 threads, 4x4 per thread.
__global__ __launch_bounds__(256) void k_nodeproj(const float* __restrict__ x,
                                                  const float* __restrict__ Wt,
                                                  float* __restrict__ xl, int N) {
  __shared__ float4 As4[64][33];  // [row][k/4], padded to 33 -> 2-way max on reads
  __shared__ float Bt[64][64];    // [k within chunk][j]
  int tid = threadIdx.x;
  int m0 = blockIdx.x * 64;
  int n0 = blockIdx.y * 64;

  // stage A (64 rows x 128 floats), coalesced global float4 loads
  for (int f = tid; f < 64 * 32; f += 256) {
    int r = f >> 5;         // row 0..63
    int k4 = f & 31;        // float4 index 0..31
    int gr = m0 + r;
    float4 v = make_float4(0.f, 0.f, 0.f, 0.f);
    if (gr < N) v = *(const float4*)(x + (size_t)gr * DIN + k4 * 4);
    As4[r][k4] = v;
  }

  int tm = tid & 15;        // 16 row-groups; rows tm + 16*i
  int tn = tid >> 4;        // 16 col-groups; cols tn*4 + j
  float acc[4][4] = {};

  for (int kc = 0; kc < 2; ++kc) {
    __syncthreads();
    for (int f = tid; f < 64 * 16; f += 256) {
      int kk = f >> 4, j4 = (f & 15) << 2;
      *(float4*)&Bt[kk][j4] = *(const float4*)(Wt + (size_t)(kc * 64 + kk) * 256 + n0 + j4);
    }
    __syncthreads();
#pragma unroll 4
    for (int kx = 0; kx < 16; ++kx) {
      int kidx = kc * 16 + kx;
      float4 a0 = As4[tm][kidx];
      float4 a1 = As4[tm + 16][kidx];
      float4 a2 = As4[tm + 32][kidx];
      float4 a3 = As4[tm + 48][kidx];
      float4 b0 = *(const float4*)&Bt[kx * 4 + 0][tn * 4];
      float4 b1 = *(const float4*)&Bt[kx * 4 + 1][tn * 4];
      float4 b2 = *(const float4*)&Bt[kx * 4 + 2][tn * 4];
      float4 b3 = *(const float4*)&Bt[kx * 4 + 3][tn * 4];
      const float* av[4] = {&a0.x, &a1.x, &a2.x, &a3.x};
      const float* bv[4] = {&b0.x, &b1.x, &b2.x, &b3.x};
#pragma unroll
      for (int i = 0; i < 4; ++i) {
#pragma unroll
        for (int t = 0; t < 4; ++t) {
#pragma unroll
          for (int j = 0; j < 4; ++j) acc[i][j] += av[i][t] * bv[t][j];
        }
      }
    }
  }

#pragma unroll
  for (int i = 0; i < 4; ++i) {
    int gr = m0 + tm + 16 * i;
    if (gr < N) {
      *(float4*)(xl + (size_t)gr * 256 + n0 + tn * 4) =
          make_float4(acc[i][0], acc[i][1], acc[i][2], acc[i][3]);
    }
  }
}

// ---------------- alpha_l/alpha_r: wave per node, shfl reduce --------------
__global__ __launch_bounds__(256) void k_alpha(const float* __restrict__ xl,
                                               const float* __restrict__ att_l,
                                               const float* __restrict__ att_r,
                                               float* __restrict__ al,
                                               float* __restrict__ ar, int N) {
  int wv = (blockIdx.x * 256 + threadIdx.x) >> 6;
  int lane = threadIdx.x & 63;
  if (wv >= N) return;
  float pl[H], pr[H];
#pragma unroll
  for (int h = 0; h < H; ++h) {
    float v = xl[(size_t)wv * 256 + h * 64 + lane];
    pl[h] = v * att_l[h * 64 + lane];
    pr[h] = v * att_r[h * 64 + lane];
  }
#pragma unroll
  for (int off = 32; off > 0; off >>= 1) {
#pragma unroll
    for (int h = 0; h < H; ++h) {
      pl[h] += __shfl_xor(pl[h], off);
      pr[h] += __shfl_xor(pr[h], off);
    }
  }
  if (lane == 0) {
#pragma unroll
    for (int h = 0; h < H; ++h) {
      al[(size_t)wv * H + h] = pl[h];
      ar[(size_t)wv * H + h] = pr[h];
    }
  }
}

// ---------------- edge projection fused: alpha_e + e_out ------------------
__global__ __launch_bounds__(256) void k_edgeproj(const float* __restrict__ ea,
                                                  const float* __restrict__ We,
                                                  const float* __restrict__ att_e,
                                                  const float* __restrict__ ebias,
                                                  float* __restrict__ eout,
                                                  float* __restrict__ ae, int E) {
  __shared__ float sW[64 * 16];
  __shared__ float sAtt[64];
  __shared__ float sBias[16];
  int tid = threadIdx.x;
  for (int f = tid; f < 64 * 16; f += 256) sW[f] = We[f];
  if (tid < 64) sAtt[tid] = att_e[tid];
  if (tid < 16) sBias[tid] = ebias[tid];
  __syncthreads();
  int e = blockIdx.x * 256 + tid;
  if (e >= E) return;
  float a[16];
  {
    const float4* p = (const float4*)(ea + (size_t)e * EIN);
    float4 v0 = p[0], v1 = p[1], v2 = p[2], v3 = p[3];
    a[0]=v0.x; a[1]=v0.y; a[2]=v0.z; a[3]=v0.w;
    a[4]=v1.x; a[5]=v1.y; a[6]=v1.z; a[7]=v1.w;
    a[8]=v2.x; a[9]=v2.y; a[10]=v2.z; a[11]=v2.w;
    a[12]=v3.x; a[13]=v3.y; a[14]=v3.z; a[15]=v3.w;
  }
  float emax[16];
#pragma unroll
  for (int c = 0; c < 16; ++c) emax[c] = -1e30f;
#pragma unroll
  for (int h = 0; h < H; ++h) {
    float acc_ae = 0.f;
#pragma unroll
    for (int c = 0; c < 16; ++c) {
      float s = 0.f;
      const float* wrow = &sW[(h * 16 + c) * 16];
#pragma unroll
      for (int k = 0; k < 16; ++k) s += a[k] * wrow[k];
      acc_ae += s * sAtt[h * 16 + c];
      emax[c] = fmaxf(emax[c], s);
    }
    ae[(size_t)e * H + h] = acc_ae;
  }
  float4 o[4];
#pragma unroll
  for (int q = 0; q < 4; ++q) {
    float r0 = fmaxf(emax[q*4+0] + sBias[q*4+0], 0.f);
    float r1 = fmaxf(emax[q*4+1] + sBias[q*4+1], 0.f);
    float r2 = fmaxf(emax[q*4+2] + sBias[q*4+2], 0.f);
    float r3 = fmaxf(emax[q*4+3] + sBias[q*4+3], 0.f);
    o[q] = make_float4(r0, r1, r2, r3);
  }
  float4* op = (float4*)(eout + (size_t)e * EOUT);
  op[0]=o[0]; op[1]=o[1]; op[2]=o[2]; op[3]=o[3];
}

// ---------------- CSR build ------------------------------------------------
__global__ __launch_bounds__(256) void k_hist(const int* __restrict__ ei,
                                              int* __restrict__ cnt, int E) {
  int e = blockIdx.x * 256 + threadIdx.x;
  if (e < E) atomicAdd(&cnt[ei[E + e]], 1);
}

__global__ __launch_bounds__(256) void k_scan1(const int* __restrict__ cnt,
                                               int* __restrict__ offs,
                                               int* __restrict__ bsum, int N) {
  __shared__ int s[256];
  int i = blockIdx.x * 256 + threadIdx.x;
  int v = (i < N) ? cnt[i] : 0;
  s[threadIdx.x] = v;
  __syncthreads();
  for (int off = 1; off < 256; off <<= 1) {
    int t = (threadIdx.x >= off) ? s[threadIdx.x - off] : 0;
    __syncthreads();
    s[threadIdx.x] += t;
    __syncthreads();
  }
  if (i < N) offs[i] = s[threadIdx.x] - v;
  if (threadIdx.x == 255) bsum[blockIdx.x] = s[255];
}

__global__ __launch_bounds__(256) void k_scan2(const int* __restrict__ bsum,
                                               int* __restrict__ boffs, int NB) {
  __shared__ int s[256];
  int v = (threadIdx.x < NB) ? bsum[threadIdx.x] : 0;
  s[threadIdx.x] = v;
  __syncthreads();
  for (int off = 1; off < 256; off <<= 1) {
    int t = (threadIdx.x >= off) ? s[threadIdx.x - off] : 0;
    __syncthreads();
    s[threadIdx.x] += t;
    __syncthreads();
  }
  if (threadIdx.x < NB) boffs[threadIdx.x] = s[threadIdx.x] - v;
}

__global__ __launch_bounds__(256) void k_scan3(int* __restrict__ offs,
                                               const int* __restrict__ boffs,
                                               int* __restrict__ cursor, int N) {
  int i = blockIdx.x * 256 + threadIdx.x;
  if (i < N) {
    int o = offs[i] + boffs[blockIdx.x];
    offs[i] = o;
    cursor[i] = o;
  }
}

__global__ __launch_bounds__(256) void k_scatter(const int* __restrict__ ei,
                                                 int* __restrict__ cursor,
                                                 int* __restrict__ csr, int E) {
  int e = blockIdx.x * 256 + threadIdx.x;
  if (e < E) {
    int d = ei[E + e];
    int p = atomicAdd(&cursor[d], 1);
    csr[p] = e;
  }
}

// ---------------- per-node softmax + aggregation (wave per node) -----------
__global__ __launch_bounds__(256) void k_agg(const float* __restrict__ xl,
                                             const float* __restrict__ al,
                                             const float* __restrict__ ar,
                                             const float* __restrict__ ae,
                                             const int* __restrict__ ei,
                                             const int* __restrict__ csr,
                                             const int* __restrict__ offs,
                                             const int* __restrict__ cnt,
                                             const float* __restrict__ nbias,
                                             float* __restrict__ out, int N, int E) {
  int wv = (blockIdx.x * 256 + threadIdx.x) >> 6;
  int lane = threadIdx.x & 63;
  if (wv >= N) return;
  int n = wv;
  int deg = cnt[n];
  int start = offs[n];
  float arn[H];
#pragma unroll
  for (int h = 0; h < H; ++h) arn[h] = ar[(size_t)n * H + h];
  float m[H], s[H], acc[H];
#pragma unroll
  for (int h = 0; h < H; ++h) { m[h] = -INFINITY; s[h] = 0.f; acc[h] = 0.f; }

  for (int i = 0; i < deg; ++i) {
    int eid = csr[start + i];
    int src = ei[eid];
    const float* xs = xl + (size_t)src * 256;
#pragma unroll
    for (int h = 0; h < H; ++h) {
      float lg = al[(size_t)src * H + h] + arn[h] + ae[(size_t)eid * H + h];
      lg = (lg >= 0.f) ? lg : NEG_SLOPE * lg;
      float xv = xs[h * 64 + lane];
      float nm = fmaxf(m[h], lg);
      float scale = __expf(m[h] - nm);   // 0 when m was -inf
      float p = __expf(lg - nm);
      s[h] = s[h] * scale + p;
      acc[h] = acc[h] * scale + p * xv;
      m[h] = nm;
    }
  }
  float best = -1e30f;
#pragma unroll
  for (int h = 0; h < H; ++h) best = fmaxf(best, acc[h] / (s[h] + 1e-16f));
  out[(size_t)n * DOUT + lane] = fmaxf(best + nbias[lane], 0.f);
}

// ---------------- launcher -------------------------------------------------
extern "C" void kernel_launch(void* const* d_in, const int* in_sizes, int n_in,
                              void* d_out, int out_size, void* d_ws, size_t ws_size,
                              hipStream_t stream) {
  const float* x     = (const float*)d_in[0];
  const float* ea    = (const float*)d_in[1];
  const int*   ei    = (const int*)d_in[2];
  const float* Wl    = (const float*)d_in[3];
  const float* We    = (const float*)d_in[4];
  const float* att_l = (const float*)d_in[5];
  const float* att_r = (const float*)d_in[6];
  const float* att_e = (const float*)d_in[7];
  const float* nbias = (const float*)d_in[8];
  const float* ebias = (const float*)d_in[9];

  int N = in_sizes[0] / DIN;
  int E = in_sizes[1] / EIN;

  float* out  = (float*)d_out;                       // [N*DOUT]
  float* eout = (float*)d_out + (size_t)N * DOUT;    // [E*EOUT]

  char* w = (char*)d_ws;
  auto alloc = [&](size_t bytes) -> void* {
    void* p = (void*)w;
    w += (bytes + 255) & ~(size_t)255;
    return p;
  };
  float* xl   = (float*)alloc((size_t)N * 256 * 4);
  float* al   = (float*)alloc((size_t)N * H * 4);
  float* ar   = (float*)alloc((size_t)N * H * 4);
  float* aeW  = (float*)alloc((size_t)E * H * 4);
  float* Wt   = (float*)alloc(128 * 256 * 4);
  int* cnt    = (int*)alloc((size_t)N * 4);
  int* offs   = (int*)alloc((size_t)N * 4);
  int* cur    = (int*)alloc((size_t)N * 4);
  int* bsum   = (int*)alloc(256 * 4);
  int* boffs  = (int*)alloc(256 * 4);
  int* csr    = (int*)alloc((size_t)E * 4);

  hipMemsetAsync(cnt, 0, (size_t)N * 4, stream);

  k_transW<<<128, 256, 0, stream>>>(Wl, Wt);
  dim3 gnp((N + 63) / 64, 4);
  k_nodeproj<<<gnp, 256, 0, stream>>>(x, Wt, xl, N);
  k_alpha<<<(N * 64 + 255) / 256, 256, 0, stream>>>(xl, att_l, att_r, al, ar, N);
  k_edgeproj<<<(E + 255) / 256, 256, 0, stream>>>(ea, We, att_e, ebias, eout, aeW, E);
  k_hist<<<(E + 255) / 256, 256, 0, stream>>>(ei, cnt, E);
  int NB = (N + 255) / 256;
  k_scan1<<<NB, 256, 0, stream>>>(cnt, offs, bsum, N);
  k_scan2<<<1, 256, 0, stream>>>(bsum, boffs, NB);
  k_scan3<<<NB, 256, 0, stream>>>(offs, boffs, cur, N);
  k_scatter<<<(E + 255) / 256, 256, 0, stream>>>(ei, cur, csr, E);
  k_agg<<<(N * 64 + 255) / 256, 256, 0, stream>>>(xl, al, ar, aeW, ei, csr, offs, cnt,
                                                  nbias, out, N, E);
}